// Round 10
// baseline (1055.305 us; speedup 1.0000x reference)
//
#include <hip/hip_runtime.h>

#define NMOV 100000
#define NUSR 50000
#define NN   150000
#define DIM  128
#define HID  256
#define NE   500000

#define MBLK 128           // rows per block (all node-tiled kernels)
#define LDK  264           // LDS row stride in shorts for the A/h tile
#define NGRID ((NN + MBLK - 1) / MBLK)   // 1172
#define NB_SCAN ((NN + 255) / 256)   // 586
#define NB_DEG  ((NE + 255) / 256)   // 1954
#define NB_CVX  (NN * DIM / 8 / 256) // 9375
#define NB_CVW  64

typedef __attribute__((ext_vector_type(8))) short bf16x8;
typedef __attribute__((ext_vector_type(4))) float f32x4;

__device__ __forceinline__ short f2bf(float f) {
  union { float f; unsigned u; } v; v.f = f;
  unsigned r = (v.u + 0x7fffu + ((v.u >> 16) & 1u)) >> 16;   // RNE
  return (short)r;
}
__device__ __forceinline__ float bf2f(short s) {
  union { unsigned u; float f; } v;
  v.u = ((unsigned)(unsigned short)s) << 16;
  return v.f;
}

// find local row d in [0,MBLK) with rp_s[d] <= j < rp_s[d+1]; rp_s ascending
__device__ __forceinline__ int bsearch_row(const int* rp_s, int j) {
  int lo = 0, hi = MBLK;
#pragma unroll
  for (int it = 0; it < 7; ++it) {    // 2^7 = MBLK
    int mid = (lo + hi) >> 1;
    bool ge = (j >= rp_s[mid]);
    lo = ge ? mid : lo;
    hi = ge ? hi : mid;
  }
  return lo;
}

// ================= prep: deg + convx + convw merged (block-range split) =========
__global__ __launch_bounds__(256) void prep_kernel(
    const int* __restrict__ dst, int* __restrict__ degi,
    const float* __restrict__ movie, const float* __restrict__ user,
    short* __restrict__ xb,
    const float* __restrict__ Wl1, const float* __restrict__ Wr1,
    const float* __restrict__ Wl2, const float* __restrict__ Wr2,
    short* __restrict__ Wf1, short* __restrict__ Wf2) {
  int blk = blockIdx.x;
  int tid = threadIdx.x;
  if (blk < NB_DEG) {
    int e = blk * 256 + tid;
    if (e < NE) atomicAdd(&degi[dst[e]], 1);
    return;
  }
  blk -= NB_DEG;
  if (blk < NB_CVX) {
    int c = blk * 256 + tid;                       // chunk of 8
    size_t base = (size_t)c * 8;
    const float* srcp = (base < (size_t)NMOV * DIM) ? (movie + base)
                                                    : (user + (base - (size_t)NMOV * DIM));
    float4 v0 = ((const float4*)srcp)[0];
    float4 v1 = ((const float4*)srcp)[1];
    short4 s0 = make_short4(f2bf(v0.x), f2bf(v0.y), f2bf(v0.z), f2bf(v0.w));
    short4 s1 = make_short4(f2bf(v1.x), f2bf(v1.y), f2bf(v1.z), f2bf(v1.w));
    *(short4*)(xb + base)     = s0;
    *(short4*)(xb + base + 4) = s1;
    return;
  }
  blk -= NB_CVX;
  {
    int t = blk * 256 + tid;   // 2*16*8*64 = 16384 threads
    int stage = t >> 13;
    int r = t & 8191;
    int n    = r >> 9;
    int kk   = (r >> 6) & 7;
    int lane = r & 63;
    int ncol  = n * 16 + (lane & 15);
    int kbase = kk * 32 + (lane >> 4) * 8;
    short vals[8];
#pragma unroll
    for (int jj = 0; jj < 8; jj++) {
      int k = kbase + jj;
      float v;
      if (stage == 0)
        v = (k < 128) ? Wl1[(size_t)k * HID + ncol] : Wr1[(size_t)(k - 128) * HID + ncol];
      else
        v = (ncol < 128) ? Wl2[(size_t)k * DIM + ncol] : Wr2[(size_t)k * DIM + (ncol - 128)];
      vals[jj] = f2bf(v);
    }
    short* outp = (stage == 0 ? Wf1 : Wf2) + ((size_t)(n * 8 + kk) << 9) + lane * 8;
    *(short4*)(outp)     = make_short4(vals[0], vals[1], vals[2], vals[3]);
    *(short4*)(outp + 4) = make_short4(vals[4], vals[5], vals[6], vals[7]);
  }
}

// ================= CSR scans =================
__global__ __launch_bounds__(256) void scan1_kernel(const int* __restrict__ degi,
                                                    int* __restrict__ pre,
                                                    int* __restrict__ bsum) {
  __shared__ int s[256];
  int tid = threadIdx.x;
  int i = blockIdx.x * 256 + tid;
  int v = (i < NN) ? degi[i] : 0;
  s[tid] = v;
  __syncthreads();
#pragma unroll
  for (int off = 1; off < 256; off <<= 1) {
    int t = (tid >= off) ? s[tid - off] : 0;
    __syncthreads();
    s[tid] += t;
    __syncthreads();
  }
  if (i < NN) pre[i] = s[tid] - v;
  if (tid == 255) bsum[blockIdx.x] = s[255];
}

__global__ __launch_bounds__(256) void scan23_kernel(const int* __restrict__ pre,
                                                     const int* __restrict__ bsum,
                                                     int* __restrict__ rowptr) {
  __shared__ int sm[256];
  int tid = threadIdx.x;
  int nb = blockIdx.x;
  int v = 0;
  for (int i = tid; i < nb; i += 256) v += bsum[i];   // <=3 iters
  sm[tid] = v;
  __syncthreads();
#pragma unroll
  for (int off = 128; off > 0; off >>= 1) {
    if (tid < off) sm[tid] += sm[tid + off];
    __syncthreads();
  }
  int base = sm[0];
  int i = nb * 256 + tid;
  if (i < NN) rowptr[i] = pre[i] + base;
  if (i == 0) rowptr[NN] = NE;
}

// stores (src, edge_id) per CSR slot
__global__ __launch_bounds__(256) void csr_scatter_kernel(const int* __restrict__ src,
                                                          const int* __restrict__ dst,
                                                          const int* __restrict__ rowptr,
                                                          int* __restrict__ cnt,
                                                          int2* __restrict__ epk) {
  int e = blockIdx.x * 256 + threadIdx.x;
  if (e >= NE) return;
  int d = dst[e];
  int pos = rowptr[d] + atomicAdd(&cnt[d], 1);
  epk[pos] = make_int2(src[e], e);
}

// ================= fused MFMA: edge-parallel gather1 + both GEMMs ==================
// Gather is EDGE-parallel: the block's 128 dst rows give a contiguous CSR slice;
// groups stream independent edges (2 in flight), LDS-atomic f32 accumulate, local
// dst found by 7-step bsearch over the LDS rowptr slice. Then the tile is built
// and the two GEMMs run as before. LDS 130.5 KB -> 1 block/CU.
__global__ __launch_bounds__(512, 2) void fused_mfma_kernel(
    const int* __restrict__ rowptr, const int2* __restrict__ epk,
    const short* __restrict__ xb, short* __restrict__ hW_out,
    const short* __restrict__ Wf1, const float* __restrict__ bl1,
    const short* __restrict__ Wf2, const float* __restrict__ bl2,
    float* __restrict__ dref) {
  __shared__ __align__(16) short tile[MBLK][LDK];    // 67.6 KB
  __shared__ __align__(16) float accum[MBLK][DIM];   // 64 KB
  __shared__ int rp_s[MBLK + 1];                     // 516 B
  const int tid = threadIdx.x;
  const int row0 = blockIdx.x * MBLK;
  const int g = tid >> 4;          // 0..31
  const int l = tid & 15;

  // ---- stage 0: rowptr slice, zero accum, own-x rows into tile x-half ----
  if (tid <= MBLK) rp_s[tid] = rowptr[min(row0 + tid, NN)];
  for (int idx = tid; idx < MBLK * DIM / 4; idx += 512)
    ((float4*)accum)[idx] = make_float4(0.f, 0.f, 0.f, 0.f);
  for (int rr = g; rr < MBLK; rr += 32) {
    int row = row0 + rr;
    bf16x8 xv = {0, 0, 0, 0, 0, 0, 0, 0};
    if (row < NN) xv = *(const bf16x8*)(xb + (size_t)row * DIM + l * 8);
    *(bf16x8*)&tile[rr][DIM + l * 8] = xv;
  }
  __syncthreads();

  // ---- stage A: edge-parallel accumulate (2 edges in flight per group) ----
  {
    int jb = rp_s[0], je = rp_s[MBLK];
    for (int j = jb + g; j < je; j += 64) {
      int j2 = j + 32;
      bool has2 = (j2 < je);
      int s1 = epk[j].x;
      int s2 = has2 ? epk[j2].x : s1;
      bf16x8 r1 = *(const bf16x8*)(xb + (size_t)s1 * DIM + l * 8);
      bf16x8 r2 = *(const bf16x8*)(xb + (size_t)s2 * DIM + l * 8);
      int d1 = bsearch_row(rp_s, j);
      float* a1 = &accum[d1][l * 8];
#pragma unroll
      for (int k = 0; k < 8; k++) atomicAdd(&a1[k], bf2f(r1[k]));
      if (has2) {
        int d2 = bsearch_row(rp_s, j2);
        float* a2 = &accum[d2][l * 8];
#pragma unroll
        for (int k = 0; k < 8; k++) atomicAdd(&a2[k], bf2f(r2[k]));
      }
    }
  }
  __syncthreads();

  // ---- stage B: mean -> bf16 into tile A-half ----
  for (int rr = g; rr < MBLK; rr += 32) {
    int deg = rp_s[rr + 1] - rp_s[rr];
    float inv = 1.0f / fmaxf((float)deg, 1.0f);
    bf16x8 ov;
#pragma unroll
    for (int k = 0; k < 8; k++) ov[k] = f2bf(accum[rr][l * 8 + k] * inv);
    *(bf16x8*)&tile[rr][l * 8] = ov;
  }
  __syncthreads();

  const int lane = tid & 63;
  const int wv   = tid >> 6;          // 0..7
  const int c    = lane & 15;
  const int quad = lane >> 4;
  const int wrow = (wv & 3) * 32;     // row quarter (32 rows = 2 groups of 16)
  const int ch   = wv >> 2;           // col half

  // ---- stage 1: h = relu(A_cat @ W1 + bl1) -> LDS ----
  {
    bf16x8 af[2][8];
#pragma unroll
    for (int rg = 0; rg < 2; rg++)
#pragma unroll
      for (int kk = 0; kk < 8; kk++)
        af[rg][kk] = *(const bf16x8*)&tile[wrow + rg * 16 + c][kk * 32 + quad * 8];
    __syncthreads();                  // A in regs everywhere -> safe to overwrite tile

#pragma unroll 2
    for (int nn = 0; nn < 8; nn++) {
      int n = ch * 8 + nn;
      const short* wq = Wf1 + ((size_t)(n * 8) << 9) + lane * 8;
      bf16x8 bw[8];
#pragma unroll
      for (int kk = 0; kk < 8; kk++)
        bw[kk] = *(const bf16x8*)(wq + ((size_t)kk << 9));
      f32x4 a0 = {0.f, 0.f, 0.f, 0.f}, a1 = {0.f, 0.f, 0.f, 0.f};
      __builtin_amdgcn_s_setprio(1);
#pragma unroll
      for (int kk = 0; kk < 8; kk++) {
        a0 = __builtin_amdgcn_mfma_f32_16x16x32_bf16(af[0][kk], bw[kk], a0, 0, 0, 0);
        a1 = __builtin_amdgcn_mfma_f32_16x16x32_bf16(af[1][kk], bw[kk], a1, 0, 0, 0);
      }
      __builtin_amdgcn_s_setprio(0);
      float bv = bl1[n * 16 + c];
#pragma unroll
      for (int i = 0; i < 4; i++) {
        tile[wrow +      quad * 4 + i][n * 16 + c] = f2bf(fmaxf(a0[i] + bv, 0.0f));
        tile[wrow + 16 + quad * 4 + i][n * 16 + c] = f2bf(fmaxf(a1[i] + bv, 0.0f));
      }
    }
  }
  __syncthreads();

  // ---- stage 2: [hW | partial+bl2] -> tile (both halves bf16), then stream out ----
  {
    bf16x8 af[2][8];
#pragma unroll
    for (int rg = 0; rg < 2; rg++)
#pragma unroll
      for (int kk = 0; kk < 8; kk++)
        af[rg][kk] = *(const bf16x8*)&tile[wrow + rg * 16 + c][kk * 32 + quad * 8];
    __syncthreads();                   // all waves done reading h -> safe to overwrite

#pragma unroll 2
    for (int nn = 0; nn < 8; nn++) {
      int n = ch * 8 + nn;
      const short* wq = Wf2 + ((size_t)(n * 8) << 9) + lane * 8;
      bf16x8 bw[8];
#pragma unroll
      for (int kk = 0; kk < 8; kk++)
        bw[kk] = *(const bf16x8*)(wq + ((size_t)kk << 9));
      f32x4 a0 = {0.f, 0.f, 0.f, 0.f}, a1 = {0.f, 0.f, 0.f, 0.f};
      __builtin_amdgcn_s_setprio(1);
#pragma unroll
      for (int kk = 0; kk < 8; kk++) {
        a0 = __builtin_amdgcn_mfma_f32_16x16x32_bf16(af[0][kk], bw[kk], a0, 0, 0, 0);
        a1 = __builtin_amdgcn_mfma_f32_16x16x32_bf16(af[1][kk], bw[kk], a1, 0, 0, 0);
      }
      __builtin_amdgcn_s_setprio(0);
      int col = n * 16 + c;
      float bv = (ch == 1) ? bl2[col - 128] : 0.0f;   // bias only on the Wr2 half
#pragma unroll
      for (int i = 0; i < 4; i++) {
        tile[wrow +      quad * 4 + i][col] = f2bf(a0[i] + bv);
        tile[wrow + 16 + quad * 4 + i][col] = f2bf(a1[i] + bv);
      }
    }
  }
  __syncthreads();

  // stream both halves out coalesced: hW -> hW_out; partial bf16 -> first 256B
  // of the node's f32 dref row (gather2 reads it there before overwriting)
  for (int idx = tid; idx < MBLK * 32; idx += 512) {
    int r   = idx >> 5;
    int c16 = idx & 31;
    int row = row0 + r;
    if (row < NN) {
      int4 v = *(const int4*)&tile[r][c16 * 8];
      if (c16 < 16)
        *(int4*)(hW_out + (size_t)row * DIM + c16 * 8) = v;
      else
        *(int4*)((short*)(dref + (size_t)row * DIM) + (c16 - 16) * 8) = v;
    }
  }
}

// ================= gather2: edge-parallel; dref = partial(bf16) + mean(hWb[src]) =====
__global__ __launch_bounds__(512, 4) void gather2_kernel(const int* __restrict__ rowptr,
                                                         const int2* __restrict__ epk,
                                                         const short* __restrict__ hWb,
                                                         short* __restrict__ drefb,
                                                         float* dref) {
  __shared__ __align__(16) float accum[MBLK][DIM];   // 64 KB -> 2 blocks/CU
  __shared__ int rp_s[MBLK + 1];
  const int tid = threadIdx.x;
  const int row0 = blockIdx.x * MBLK;
  const int g = tid >> 4;
  const int l = tid & 15;

  if (tid <= MBLK) rp_s[tid] = rowptr[min(row0 + tid, NN)];
  for (int idx = tid; idx < MBLK * DIM / 4; idx += 512)
    ((float4*)accum)[idx] = make_float4(0.f, 0.f, 0.f, 0.f);
  __syncthreads();

  {
    int jb = rp_s[0], je = rp_s[MBLK];
    for (int j = jb + g; j < je; j += 64) {
      int j2 = j + 32;
      bool has2 = (j2 < je);
      int s1 = epk[j].x;
      int s2 = has2 ? epk[j2].x : s1;
      bf16x8 r1 = *(const bf16x8*)(hWb + (size_t)s1 * DIM + l * 8);
      bf16x8 r2 = *(const bf16x8*)(hWb + (size_t)s2 * DIM + l * 8);
      int d1 = bsearch_row(rp_s, j);
      float* a1 = &accum[d1][l * 8];
#pragma unroll
      for (int k = 0; k < 8; k++) atomicAdd(&a1[k], bf2f(r1[k]));
      if (has2) {
        int d2 = bsearch_row(rp_s, j2);
        float* a2 = &accum[d2][l * 8];
#pragma unroll
        for (int k = 0; k < 8; k++) atomicAdd(&a2[k], bf2f(r2[k]));
      }
    }
  }
  __syncthreads();

  // finalize: fin = bf16-partial(in dref row) + accum*inv; write f32 + bf16 shadow
  for (int rr = g; rr < MBLK; rr += 32) {
    int row = row0 + rr;
    if (row >= NN) continue;
    int deg = rp_s[rr + 1] - rp_s[rr];
    float inv = 1.0f / fmaxf((float)deg, 1.0f);
    float* dr = dref + (size_t)row * DIM;
    bf16x8 p = *(const bf16x8*)((const short*)dr + l * 8);
    float fin[8];
    bf16x8 ov;
#pragma unroll
    for (int k = 0; k < 8; k++) {
      fin[k] = bf2f(p[k]) + accum[rr][l * 8 + k] * inv;
      ov[k] = f2bf(fin[k]);
    }
    *(float4*)(dr + l * 8)     = make_float4(fin[0], fin[1], fin[2], fin[3]);
    *(float4*)(dr + l * 8 + 4) = make_float4(fin[4], fin[5], fin[6], fin[7]);
    *(bf16x8*)(drefb + (size_t)row * DIM + l * 8) = ov;
  }
}

// ================= score: edge-parallel, dst rows staged in LDS =================
// One random src-row read per edge; dot against the LDS-resident dst row.
__global__ __launch_bounds__(512, 4) void score_kernel(const int* __restrict__ rowptr,
                                                       const int2* __restrict__ epk,
                                                       const short* __restrict__ drefb,
                                                       float* __restrict__ out) {
  __shared__ __align__(16) short sh_d[MBLK][DIM];    // 32 KB
  __shared__ int rp_s[MBLK + 1];
  const int tid = threadIdx.x;
  const int row0 = blockIdx.x * MBLK;
  const int g = tid >> 4;
  const int l = tid & 15;

  if (tid <= MBLK) rp_s[tid] = rowptr[min(row0 + tid, NN)];
  for (int rr = g; rr < MBLK; rr += 32) {
    int row = row0 + rr;
    bf16x8 dv = {0, 0, 0, 0, 0, 0, 0, 0};
    if (row < NN) dv = *(const bf16x8*)(drefb + (size_t)row * DIM + l * 8);
    *(bf16x8*)&sh_d[rr][l * 8] = dv;
  }
  __syncthreads();

  int jb = rp_s[0], je = rp_s[MBLK];
  for (int j = jb + g; j < je; j += 64) {
    int j2 = j + 32;
    bool has2 = (j2 < je);
    int2 p1 = epk[j];
    int2 p2 = has2 ? epk[j2] : p1;
    bf16x8 r1 = *(const bf16x8*)(drefb + (size_t)p1.x * DIM + l * 8);
    bf16x8 r2 = *(const bf16x8*)(drefb + (size_t)p2.x * DIM + l * 8);
    int d1 = bsearch_row(rp_s, j);
    int d2 = has2 ? bsearch_row(rp_s, j2) : d1;
    bf16x8 q1 = *(const bf16x8*)&sh_d[d1][l * 8];
    bf16x8 q2 = *(const bf16x8*)&sh_d[d2][l * 8];
    float s1 = 0.f, s2 = 0.f;
#pragma unroll
    for (int k = 0; k < 8; k++) {
      s1 += bf2f(r1[k]) * bf2f(q1[k]);
      s2 += bf2f(r2[k]) * bf2f(q2[k]);
    }
#pragma unroll
    for (int off = 1; off < 16; off <<= 1) {
      s1 += __shfl_xor(s1, off, 16);
      s2 += __shfl_xor(s2, off, 16);
    }
    if (l == 0) {
      out[p1.y] = s1;
      if (has2) out[p2.y] = s2;
    }
  }
}

extern "C" void kernel_launch(void* const* d_in, const int* in_sizes, int n_in,
                              void* d_out, int out_size, void* d_ws, size_t ws_size,
                              hipStream_t stream) {
  const int* ei    = (const int*)d_in[0];
  const int* src   = ei;
  const int* dst   = ei + NE;
  // d_in[1] = edge_attr (unused by the reference)
  const float* movie = (const float*)d_in[2];
  const float* user  = (const float*)d_in[3];
  const float* Wl1   = (const float*)d_in[4];
  const float* bl1   = (const float*)d_in[5];
  const float* Wr1   = (const float*)d_in[6];
  const float* Wl2   = (const float*)d_in[7];
  const float* bl2   = (const float*)d_in[8];
  const float* Wr2   = (const float*)d_in[9];

  float* out  = (float*)d_out;       // [NE] ratings
  float* dref = out + NE;            // [NN*DIM] refined (f32 output; also carries
                                     //   the bf16 partial in each row's first 256B)

  // workspace (~84 MB): ints | epk | xb(+drefb alias) | hWb | Wf1 | Wf2
  int* degi   = (int*)d_ws;                    // [NN] (zeroed)
  int* cnt    = degi + NN;                     // [NN] (zeroed)
  int* pre    = cnt + NN;                      // [NN]
  int* bsum   = pre + NN;                      // [1024]
  int* rowptr = bsum + 1024;                   // [NN+1]
  int2* epk   = (int2*)(((uintptr_t)(rowptr + NN + 1) + 7) & ~(uintptr_t)7);  // [NE]
  short* xb   = (short*)(((uintptr_t)(epk + NE) + 15) & ~(uintptr_t)15);  // [NN*DIM] bf16
  short* hWb  = xb + (size_t)NN * DIM;         // [NN*DIM] bf16 (h@Wl2, from fused)
  short* Wf1  = hWb + (size_t)NN * DIM;        // [65536]
  short* Wf2  = Wf1 + 65536;                   // [65536]
  short* drefb = xb;                           // alias: xb dead after fused

  hipMemsetAsync(degi, 0, (size_t)2 * NN * sizeof(int), stream);

  prep_kernel<<<NB_DEG + NB_CVX + NB_CVW, 256, 0, stream>>>(
      dst, degi, movie, user, xb, Wl1, Wr1, Wl2, Wr2, Wf1, Wf2);
  scan1_kernel<<<NB_SCAN, 256, 0, stream>>>(degi, pre, bsum);
  scan23_kernel<<<NB_SCAN, 256, 0, stream>>>(pre, bsum, rowptr);
  csr_scatter_kernel<<<(NE + 255) / 256, 256, 0, stream>>>(src, dst, rowptr, cnt, epk);
  fused_mfma_kernel<<<NGRID, 512, 0, stream>>>(
      rowptr, epk, xb, hWb, Wf1, bl1, Wf2, bl2, dref);
  gather2_kernel<<<NGRID, 512, 0, stream>>>(rowptr, epk, hWb, drefb, dref);
  score_kernel<<<NGRID, 512, 0, stream>>>(rowptr, epk, drefb, out);
}

// Round 11
// 381.439 us; speedup vs baseline: 2.7666x; 2.7666x over previous
//
#include <hip/hip_runtime.h>

#define NMOV 100000
#define NUSR 50000
#define NN   150000
#define DIM  128
#define HID  256
#define NE   500000

#define MBLK 128           // rows per block (fused)
#define LDK  264           // LDS row stride in shorts for the A/h tile
#define EMAXF 2048         // fused: max staged edge-slice (block of 128 nodes; mean 427)
#define G2N  16            // gather2/score: nodes per block (256 thr / 16 lanes)
#define EMAXG 512          // gather2/score: max staged edge-slice (mean 53)
#define NB_SCAN ((NN + 255) / 256)   // 586
#define NB_DEG  ((NE + 255) / 256)   // 1954
#define NB_CVX  (NN * DIM / 8 / 256) // 9375
#define NB_CVW  64

typedef __attribute__((ext_vector_type(8))) short bf16x8;
typedef __attribute__((ext_vector_type(4))) float f32x4;

__device__ __forceinline__ short f2bf(float f) {
  union { float f; unsigned u; } v; v.f = f;
  unsigned r = (v.u + 0x7fffu + ((v.u >> 16) & 1u)) >> 16;   // RNE
  return (short)r;
}
__device__ __forceinline__ float bf2f(short s) {
  union { unsigned u; float f; } v;
  v.u = ((unsigned)(unsigned short)s) << 16;
  return v.f;
}

// ================= prep: deg + convx + convw merged (block-range split) =========
__global__ __launch_bounds__(256) void prep_kernel(
    const int* __restrict__ dst, int* __restrict__ degi,
    const float* __restrict__ movie, const float* __restrict__ user,
    short* __restrict__ xb,
    const float* __restrict__ Wl1, const float* __restrict__ Wr1,
    const float* __restrict__ Wl2, const float* __restrict__ Wr2,
    short* __restrict__ Wf1, short* __restrict__ Wf2) {
  int blk = blockIdx.x;
  int tid = threadIdx.x;
  if (blk < NB_DEG) {
    int e = blk * 256 + tid;
    if (e < NE) atomicAdd(&degi[dst[e]], 1);
    return;
  }
  blk -= NB_DEG;
  if (blk < NB_CVX) {
    int c = blk * 256 + tid;                       // chunk of 8
    size_t base = (size_t)c * 8;
    const float* srcp = (base < (size_t)NMOV * DIM) ? (movie + base)
                                                    : (user + (base - (size_t)NMOV * DIM));
    float4 v0 = ((const float4*)srcp)[0];
    float4 v1 = ((const float4*)srcp)[1];
    short4 s0 = make_short4(f2bf(v0.x), f2bf(v0.y), f2bf(v0.z), f2bf(v0.w));
    short4 s1 = make_short4(f2bf(v1.x), f2bf(v1.y), f2bf(v1.z), f2bf(v1.w));
    *(short4*)(xb + base)     = s0;
    *(short4*)(xb + base + 4) = s1;
    return;
  }
  blk -= NB_CVX;
  {
    int t = blk * 256 + tid;   // 2*16*8*64 = 16384 threads
    int stage = t >> 13;
    int r = t & 8191;
    int n    = r >> 9;
    int kk   = (r >> 6) & 7;
    int lane = r & 63;
    int ncol  = n * 16 + (lane & 15);
    int kbase = kk * 32 + (lane >> 4) * 8;
    short vals[8];
#pragma unroll
    for (int jj = 0; jj < 8; jj++) {
      int k = kbase + jj;
      float v;
      if (stage == 0)
        v = (k < 128) ? Wl1[(size_t)k * HID + ncol] : Wr1[(size_t)(k - 128) * HID + ncol];
      else
        v = (ncol < 128) ? Wl2[(size_t)k * DIM + ncol] : Wr2[(size_t)k * DIM + (ncol - 128)];
      vals[jj] = f2bf(v);
    }
    short* outp = (stage == 0 ? Wf1 : Wf2) + ((size_t)(n * 8 + kk) << 9) + lane * 8;
    *(short4*)(outp)     = make_short4(vals[0], vals[1], vals[2], vals[3]);
    *(short4*)(outp + 4) = make_short4(vals[4], vals[5], vals[6], vals[7]);
  }
}

// ================= CSR scans =================
__global__ __launch_bounds__(256) void scan1_kernel(const int* __restrict__ degi,
                                                    int* __restrict__ pre,
                                                    int* __restrict__ bsum) {
  __shared__ int s[256];
  int tid = threadIdx.x;
  int i = blockIdx.x * 256 + tid;
  int v = (i < NN) ? degi[i] : 0;
  s[tid] = v;
  __syncthreads();
#pragma unroll
  for (int off = 1; off < 256; off <<= 1) {
    int t = (tid >= off) ? s[tid - off] : 0;
    __syncthreads();
    s[tid] += t;
    __syncthreads();
  }
  if (i < NN) pre[i] = s[tid] - v;
  if (tid == 255) bsum[blockIdx.x] = s[255];
}

__global__ __launch_bounds__(256) void scan23_kernel(const int* __restrict__ pre,
                                                     const int* __restrict__ bsum,
                                                     int* __restrict__ rowptr) {
  __shared__ int sm[256];
  int tid = threadIdx.x;
  int nb = blockIdx.x;
  int v = 0;
  for (int i = tid; i < nb; i += 256) v += bsum[i];   // <=3 iters
  sm[tid] = v;
  __syncthreads();
#pragma unroll
  for (int off = 128; off > 0; off >>= 1) {
    if (tid < off) sm[tid] += sm[tid + off];
    __syncthreads();
  }
  int base = sm[0];
  int i = nb * 256 + tid;
  if (i < NN) rowptr[i] = pre[i] + base;
  if (i == 0) rowptr[NN] = NE;
}

// stores (src, edge_id) per CSR slot
__global__ __launch_bounds__(256) void csr_scatter_kernel(const int* __restrict__ src,
                                                          const int* __restrict__ dst,
                                                          const int* __restrict__ rowptr,
                                                          int* __restrict__ cnt,
                                                          int2* __restrict__ epk) {
  int e = blockIdx.x * 256 + threadIdx.x;
  if (e >= NE) return;
  int d = dst[e];
  int pos = rowptr[d] + atomicAdd(&cnt[d], 1);
  epk[pos] = make_int2(src[e], e);
}

// ================= fused MFMA: gather1 + both GEMMs, h stays in LDS =================
// R9 structure + LDS-staged edge indices: the block's contiguous CSR slice of
// src indices is loaded coalesced into es_s once, removing the rowptr/epk L2
// latency links from every per-row gather chain. Block-uniform fallback if the
// slice exceeds EMAXF. Stage-2 streams hW (bf16) and the bf16 partial (into the
// first 256B of each node's f32 dref row).
__global__ __launch_bounds__(512, 2) void fused_mfma_kernel(
    const int* __restrict__ rowptr, const int2* __restrict__ epk,
    const short* __restrict__ xb, short* __restrict__ hW_out,
    const short* __restrict__ Wf1, const float* __restrict__ bl1,
    const short* __restrict__ Wf2, const float* __restrict__ bl2,
    float* __restrict__ dref) {
  __shared__ __align__(16) short tile[MBLK][LDK];   // 67.6 KB
  __shared__ int rp_s[MBLK + 1];                    // 516 B
  __shared__ int es_s[EMAXF];                       // 8 KB  -> total ~76 KB, 2 blk/CU
  const int tid = threadIdx.x;
  const int row0 = blockIdx.x * MBLK;
  const int g = tid >> 4;          // 0..31
  const int l = tid & 15;

  // rowptr slice + own-x rows into tile x-half (independent)
  if (tid <= MBLK) rp_s[tid] = rowptr[min(row0 + tid, NN)];
  for (int rr = g; rr < MBLK; rr += 32) {
    int row = row0 + rr;
    bf16x8 xv = {0, 0, 0, 0, 0, 0, 0, 0};
    if (row < NN) xv = *(const bf16x8*)(xb + (size_t)row * DIM + l * 8);
    *(bf16x8*)&tile[rr][DIM + l * 8] = xv;
  }
  __syncthreads();

  const int jb = rp_s[0];
  const int ecnt = rp_s[MBLK] - jb;
  const bool fits = (ecnt <= EMAXF);
  if (fits) {
    for (int idx = tid; idx < ecnt; idx += 512) es_s[idx] = epk[jb + idx].x;
  }
  __syncthreads();

  // per-row mean gather (indices from LDS; 4-batch clamped)
  for (int rr = g; rr < MBLK; rr += 32) {
    int b = rp_s[rr], e = rp_s[rr + 1];
    float acc[8] = {0.f, 0.f, 0.f, 0.f, 0.f, 0.f, 0.f, 0.f};
    for (int j = b; j < e; j += 4) {
      int i1 = (j + 1 < e) ? j + 1 : j;
      int i2 = (j + 2 < e) ? j + 2 : j;
      int i3 = (j + 3 < e) ? j + 3 : j;
      int s0, s1, s2, s3;
      if (fits) {
        s0 = es_s[j - jb]; s1 = es_s[i1 - jb]; s2 = es_s[i2 - jb]; s3 = es_s[i3 - jb];
      } else {
        s0 = epk[j].x; s1 = epk[i1].x; s2 = epk[i2].x; s3 = epk[i3].x;
      }
      bf16x8 r0 = *(const bf16x8*)(xb + (size_t)s0 * DIM + l * 8);
      bf16x8 r1 = *(const bf16x8*)(xb + (size_t)s1 * DIM + l * 8);
      bf16x8 r2 = *(const bf16x8*)(xb + (size_t)s2 * DIM + l * 8);
      bf16x8 r3 = *(const bf16x8*)(xb + (size_t)s3 * DIM + l * 8);
      float m1 = (j + 1 < e) ? 1.f : 0.f;
      float m2 = (j + 2 < e) ? 1.f : 0.f;
      float m3 = (j + 3 < e) ? 1.f : 0.f;
#pragma unroll
      for (int k = 0; k < 8; k++)
        acc[k] += bf2f(r0[k]) + m1 * bf2f(r1[k]) + m2 * bf2f(r2[k]) + m3 * bf2f(r3[k]);
    }
    float inv = 1.0f / fmaxf((float)(e - b), 1.0f);
    bf16x8 ov;
#pragma unroll
    for (int k = 0; k < 8; k++) ov[k] = f2bf(acc[k] * inv);
    *(bf16x8*)&tile[rr][l * 8] = ov;
  }
  __syncthreads();

  const int lane = tid & 63;
  const int wv   = tid >> 6;          // 0..7
  const int c    = lane & 15;
  const int quad = lane >> 4;
  const int wrow = (wv & 3) * 32;     // row quarter (32 rows = 2 groups of 16)
  const int ch   = wv >> 2;           // col half

  // ---- stage 1: h = relu(A_cat @ W1 + bl1) -> LDS ----
  {
    bf16x8 af[2][8];
#pragma unroll
    for (int rg = 0; rg < 2; rg++)
#pragma unroll
      for (int kk = 0; kk < 8; kk++)
        af[rg][kk] = *(const bf16x8*)&tile[wrow + rg * 16 + c][kk * 32 + quad * 8];
    __syncthreads();                  // A in regs everywhere -> safe to overwrite tile

#pragma unroll 2
    for (int nn = 0; nn < 8; nn++) {
      int n = ch * 8 + nn;
      const short* wq = Wf1 + ((size_t)(n * 8) << 9) + lane * 8;
      bf16x8 bw[8];
#pragma unroll
      for (int kk = 0; kk < 8; kk++)
        bw[kk] = *(const bf16x8*)(wq + ((size_t)kk << 9));
      f32x4 a0 = {0.f, 0.f, 0.f, 0.f}, a1 = {0.f, 0.f, 0.f, 0.f};
      __builtin_amdgcn_s_setprio(1);
#pragma unroll
      for (int kk = 0; kk < 8; kk++) {
        a0 = __builtin_amdgcn_mfma_f32_16x16x32_bf16(af[0][kk], bw[kk], a0, 0, 0, 0);
        a1 = __builtin_amdgcn_mfma_f32_16x16x32_bf16(af[1][kk], bw[kk], a1, 0, 0, 0);
      }
      __builtin_amdgcn_s_setprio(0);
      float bv = bl1[n * 16 + c];
#pragma unroll
      for (int i = 0; i < 4; i++) {
        tile[wrow +      quad * 4 + i][n * 16 + c] = f2bf(fmaxf(a0[i] + bv, 0.0f));
        tile[wrow + 16 + quad * 4 + i][n * 16 + c] = f2bf(fmaxf(a1[i] + bv, 0.0f));
      }
    }
  }
  __syncthreads();

  // ---- stage 2: [hW | partial+bl2] -> tile (both halves bf16), then stream out ----
  {
    bf16x8 af[2][8];
#pragma unroll
    for (int rg = 0; rg < 2; rg++)
#pragma unroll
      for (int kk = 0; kk < 8; kk++)
        af[rg][kk] = *(const bf16x8*)&tile[wrow + rg * 16 + c][kk * 32 + quad * 8];
    __syncthreads();                   // all waves done reading h -> safe to overwrite

#pragma unroll 2
    for (int nn = 0; nn < 8; nn++) {
      int n = ch * 8 + nn;
      const short* wq = Wf2 + ((size_t)(n * 8) << 9) + lane * 8;
      bf16x8 bw[8];
#pragma unroll
      for (int kk = 0; kk < 8; kk++)
        bw[kk] = *(const bf16x8*)(wq + ((size_t)kk << 9));
      f32x4 a0 = {0.f, 0.f, 0.f, 0.f}, a1 = {0.f, 0.f, 0.f, 0.f};
      __builtin_amdgcn_s_setprio(1);
#pragma unroll
      for (int kk = 0; kk < 8; kk++) {
        a0 = __builtin_amdgcn_mfma_f32_16x16x32_bf16(af[0][kk], bw[kk], a0, 0, 0, 0);
        a1 = __builtin_amdgcn_mfma_f32_16x16x32_bf16(af[1][kk], bw[kk], a1, 0, 0, 0);
      }
      __builtin_amdgcn_s_setprio(0);
      int col = n * 16 + c;
      float bv = (ch == 1) ? bl2[col - 128] : 0.0f;   // bias only on the Wr2 half
#pragma unroll
      for (int i = 0; i < 4; i++) {
        tile[wrow +      quad * 4 + i][col] = f2bf(a0[i] + bv);
        tile[wrow + 16 + quad * 4 + i][col] = f2bf(a1[i] + bv);
      }
    }
  }
  __syncthreads();

  // stream both halves out coalesced: hW -> hW_out; partial bf16 -> first 256B
  // of the node's f32 dref row (gather2 reads it there before overwriting)
  for (int idx = tid; idx < MBLK * 32; idx += 512) {
    int r   = idx >> 5;
    int c16 = idx & 31;
    int row = row0 + r;
    if (row < NN) {
      int4 v = *(const int4*)&tile[r][c16 * 8];
      if (c16 < 16)
        *(int4*)(hW_out + (size_t)row * DIM + c16 * 8) = v;
      else
        *(int4*)((short*)(dref + (size_t)row * DIM) + (c16 - 16) * 8) = v;
    }
  }
}

// ================= gather2: dref = partial(bf16, in-row) + mean(hWb[src]) ============
// 16 nodes per block; block's contiguous epk src-slice staged in LDS.
__global__ __launch_bounds__(256) void gather2_kernel(const int* __restrict__ rowptr,
                                                      const int2* __restrict__ epk,
                                                      const short* __restrict__ hWb,
                                                      short* __restrict__ drefb,
                                                      float* dref) {
  __shared__ int rp_s[G2N + 1];
  __shared__ int es_s[EMAXG];
  const int tid = threadIdx.x;
  const int n0 = blockIdx.x * G2N;
  const int g = tid >> 4, l = tid & 15;

  if (tid <= G2N) rp_s[tid] = rowptr[min(n0 + tid, NN)];
  __syncthreads();
  const int jb = rp_s[0];
  const int ecnt = rp_s[G2N] - jb;
  const bool fits = (ecnt <= EMAXG);
  if (fits) {
    for (int idx = tid; idx < ecnt; idx += 256) es_s[idx] = epk[jb + idx].x;
  }
  __syncthreads();

  int node = n0 + g;
  if (node >= NN) return;
  int b = rp_s[g], e = rp_s[g + 1];
  float* dr = dref + (size_t)node * DIM;
  bf16x8 p = *(const bf16x8*)((const short*)dr + l * 8);   // hoisted bf16 partial
  float acc[8] = {0.f, 0.f, 0.f, 0.f, 0.f, 0.f, 0.f, 0.f};
  for (int j = b; j < e; j += 4) {
    int i1 = (j + 1 < e) ? j + 1 : j;
    int i2 = (j + 2 < e) ? j + 2 : j;
    int i3 = (j + 3 < e) ? j + 3 : j;
    int s0, s1, s2, s3;
    if (fits) {
      s0 = es_s[j - jb]; s1 = es_s[i1 - jb]; s2 = es_s[i2 - jb]; s3 = es_s[i3 - jb];
    } else {
      s0 = epk[j].x; s1 = epk[i1].x; s2 = epk[i2].x; s3 = epk[i3].x;
    }
    bf16x8 r0 = *(const bf16x8*)(hWb + (size_t)s0 * DIM + l * 8);
    bf16x8 r1 = *(const bf16x8*)(hWb + (size_t)s1 * DIM + l * 8);
    bf16x8 r2 = *(const bf16x8*)(hWb + (size_t)s2 * DIM + l * 8);
    bf16x8 r3 = *(const bf16x8*)(hWb + (size_t)s3 * DIM + l * 8);
    float m1 = (j + 1 < e) ? 1.f : 0.f;
    float m2 = (j + 2 < e) ? 1.f : 0.f;
    float m3 = (j + 3 < e) ? 1.f : 0.f;
#pragma unroll
    for (int k = 0; k < 8; k++)
      acc[k] += bf2f(r0[k]) + m1 * bf2f(r1[k]) + m2 * bf2f(r2[k]) + m3 * bf2f(r3[k]);
  }
  float inv = 1.0f / fmaxf((float)(e - b), 1.0f);
  float fin[8];
  bf16x8 ov;
#pragma unroll
  for (int k = 0; k < 8; k++) {
    fin[k] = bf2f(p[k]) + acc[k] * inv;
    ov[k] = f2bf(fin[k]);
  }
  *(float4*)(dr + l * 8)     = make_float4(fin[0], fin[1], fin[2], fin[3]);
  *(float4*)(dr + l * 8 + 4) = make_float4(fin[4], fin[5], fin[6], fin[7]);
  *(bf16x8*)(drefb + (size_t)node * DIM + l * 8) = ov;
}

// ================= edge scoring, CSR-node-parallel: dst row register-cached ==========
// 16 nodes per block; (src,eid) pairs staged in LDS; 1 random src row per edge.
__global__ __launch_bounds__(256) void score_kernel(const int* __restrict__ rowptr,
                                                    const int2* __restrict__ epk,
                                                    const short* __restrict__ drefb,
                                                    float* __restrict__ out) {
  __shared__ int rp_s[G2N + 1];
  __shared__ int2 es2_s[EMAXG];
  const int tid = threadIdx.x;
  const int n0 = blockIdx.x * G2N;
  const int g = tid >> 4, l = tid & 15;

  if (tid <= G2N) rp_s[tid] = rowptr[min(n0 + tid, NN)];
  __syncthreads();
  const int jb = rp_s[0];
  const int ecnt = rp_s[G2N] - jb;
  const bool fits = (ecnt <= EMAXG);
  if (fits) {
    for (int idx = tid; idx < ecnt; idx += 256) es2_s[idx] = epk[jb + idx];
  }
  __syncthreads();

  int node = n0 + g;
  if (node >= NN) return;
  int b = rp_s[g], e = rp_s[g + 1];
  if (b == e) return;
  bf16x8 d = *(const bf16x8*)(drefb + (size_t)node * DIM + l * 8);
  float f[8];
#pragma unroll
  for (int k = 0; k < 8; k++) f[k] = bf2f(d[k]);
  for (int j = b; j < e; j += 4) {
    int i1 = (j + 1 < e) ? j + 1 : j;
    int i2 = (j + 2 < e) ? j + 2 : j;
    int i3 = (j + 3 < e) ? j + 3 : j;
    int2 p0, p1, p2, p3;
    if (fits) {
      p0 = es2_s[j - jb]; p1 = es2_s[i1 - jb]; p2 = es2_s[i2 - jb]; p3 = es2_s[i3 - jb];
    } else {
      p0 = epk[j]; p1 = epk[i1]; p2 = epk[i2]; p3 = epk[i3];
    }
    bf16x8 r0 = *(const bf16x8*)(drefb + (size_t)p0.x * DIM + l * 8);
    bf16x8 r1 = *(const bf16x8*)(drefb + (size_t)p1.x * DIM + l * 8);
    bf16x8 r2 = *(const bf16x8*)(drefb + (size_t)p2.x * DIM + l * 8);
    bf16x8 r3 = *(const bf16x8*)(drefb + (size_t)p3.x * DIM + l * 8);
    float s0 = 0.f, s1 = 0.f, s2 = 0.f, s3 = 0.f;
#pragma unroll
    for (int k = 0; k < 8; k++) {
      s0 += bf2f(r0[k]) * f[k];
      s1 += bf2f(r1[k]) * f[k];
      s2 += bf2f(r2[k]) * f[k];
      s3 += bf2f(r3[k]) * f[k];
    }
#pragma unroll
    for (int off = 1; off < 16; off <<= 1) {
      s0 += __shfl_xor(s0, off, 16);
      s1 += __shfl_xor(s1, off, 16);
      s2 += __shfl_xor(s2, off, 16);
      s3 += __shfl_xor(s3, off, 16);
    }
    if (l == 0) {
      out[p0.y] = s0;
      if (j + 1 < e) out[p1.y] = s1;
      if (j + 2 < e) out[p2.y] = s2;
      if (j + 3 < e) out[p3.y] = s3;
    }
  }
}

extern "C" void kernel_launch(void* const* d_in, const int* in_sizes, int n_in,
                              void* d_out, int out_size, void* d_ws, size_t ws_size,
                              hipStream_t stream) {
  const int* ei    = (const int*)d_in[0];
  const int* src   = ei;
  const int* dst   = ei + NE;
  // d_in[1] = edge_attr (unused by the reference)
  const float* movie = (const float*)d_in[2];
  const float* user  = (const float*)d_in[3];
  const float* Wl1   = (const float*)d_in[4];
  const float* bl1   = (const float*)d_in[5];
  const float* Wr1   = (const float*)d_in[6];
  const float* Wl2   = (const float*)d_in[7];
  const float* bl2   = (const float*)d_in[8];
  const float* Wr2   = (const float*)d_in[9];

  float* out  = (float*)d_out;       // [NE] ratings
  float* dref = out + NE;            // [NN*DIM] refined (f32 output; also carries
                                     //   the bf16 partial in each row's first 256B)

  // workspace (~84 MB): ints | epk | xb(+drefb alias) | hWb | Wf1 | Wf2
  int* degi   = (int*)d_ws;                    // [NN] (zeroed)
  int* cnt    = degi + NN;                     // [NN] (zeroed)
  int* pre    = cnt + NN;                      // [NN]
  int* bsum   = pre + NN;                      // [1024]
  int* rowptr = bsum + 1024;                   // [NN+1]
  int2* epk   = (int2*)(((uintptr_t)(rowptr + NN + 1) + 7) & ~(uintptr_t)7);  // [NE]
  short* xb   = (short*)(((uintptr_t)(epk + NE) + 15) & ~(uintptr_t)15);  // [NN*DIM] bf16
  short* hWb  = xb + (size_t)NN * DIM;         // [NN*DIM] bf16 (h@Wl2, from fused)
  short* Wf1  = hWb + (size_t)NN * DIM;        // [65536]
  short* Wf2  = Wf1 + 65536;                   // [65536]
  short* drefb = xb;                           // alias: xb dead after fused

  hipMemsetAsync(degi, 0, (size_t)2 * NN * sizeof(int), stream);

  prep_kernel<<<NB_DEG + NB_CVX + NB_CVW, 256, 0, stream>>>(
      dst, degi, movie, user, xb, Wl1, Wr1, Wl2, Wr2, Wf1, Wf2);
  scan1_kernel<<<NB_SCAN, 256, 0, stream>>>(degi, pre, bsum);
  scan23_kernel<<<NB_SCAN, 256, 0, stream>>>(pre, bsum, rowptr);
  csr_scatter_kernel<<<(NE + 255) / 256, 256, 0, stream>>>(src, dst, rowptr, cnt, epk);
  fused_mfma_kernel<<<(NN + MBLK - 1) / MBLK, 512, 0, stream>>>(
      rowptr, epk, xb, hWb, Wf1, bl1, Wf2, bl2, dref);
  gather2_kernel<<<(NN + G2N - 1) / G2N, 256, 0, stream>>>(rowptr, epk, hWb, drefb, dref);
  score_kernel<<<(NN + G2N - 1) / G2N, 256, 0, stream>>>(rowptr, epk, drefb, out);
}

// Round 12
// 380.190 us; speedup vs baseline: 2.7757x; 1.0033x over previous
//
#include <hip/hip_runtime.h>

#define NMOV 100000
#define NUSR 50000
#define NN   150000
#define DIM  128
#define HID  256
#define NE   500000

#define MBLK 128           // rows per block
#define LDK  264           // LDS row stride in shorts for the A/h tile
#define NB_SCAN ((NN + 255) / 256)   // 586
#define NB_DEG  ((NE + 255) / 256)   // 1954
#define NB_CVX  (NN * DIM / 8 / 256) // 9375
#define NB_CVW  64

typedef __attribute__((ext_vector_type(8))) short bf16x8;
typedef __attribute__((ext_vector_type(4))) float f32x4;

__device__ __forceinline__ short f2bf(float f) {
  union { float f; unsigned u; } v; v.f = f;
  unsigned r = (v.u + 0x7fffu + ((v.u >> 16) & 1u)) >> 16;   // RNE
  return (short)r;
}
__device__ __forceinline__ float bf2f(short s) {
  union { unsigned u; float f; } v;
  v.u = ((unsigned)(unsigned short)s) << 16;
  return v.f;
}

// ================= prep: deg + convx + convw merged (block-range split) =========
__global__ __launch_bounds__(256) void prep_kernel(
    const int* __restrict__ dst, int* __restrict__ degi,
    const float* __restrict__ movie, const float* __restrict__ user,
    short* __restrict__ xb,
    const float* __restrict__ Wl1, const float* __restrict__ Wr1,
    const float* __restrict__ Wl2, const float* __restrict__ Wr2,
    short* __restrict__ Wf1, short* __restrict__ Wf2) {
  int blk = blockIdx.x;
  int tid = threadIdx.x;
  if (blk < NB_DEG) {
    int e = blk * 256 + tid;
    if (e < NE) atomicAdd(&degi[dst[e]], 1);
    return;
  }
  blk -= NB_DEG;
  if (blk < NB_CVX) {
    int c = blk * 256 + tid;                       // chunk of 8
    size_t base = (size_t)c * 8;
    const float* srcp = (base < (size_t)NMOV * DIM) ? (movie + base)
                                                    : (user + (base - (size_t)NMOV * DIM));
    float4 v0 = ((const float4*)srcp)[0];
    float4 v1 = ((const float4*)srcp)[1];
    short4 s0 = make_short4(f2bf(v0.x), f2bf(v0.y), f2bf(v0.z), f2bf(v0.w));
    short4 s1 = make_short4(f2bf(v1.x), f2bf(v1.y), f2bf(v1.z), f2bf(v1.w));
    *(short4*)(xb + base)     = s0;
    *(short4*)(xb + base + 4) = s1;
    return;
  }
  blk -= NB_CVX;
  {
    int t = blk * 256 + tid;   // 2*16*8*64 = 16384 threads
    int stage = t >> 13;
    int r = t & 8191;
    int n    = r >> 9;
    int kk   = (r >> 6) & 7;
    int lane = r & 63;
    int ncol  = n * 16 + (lane & 15);
    int kbase = kk * 32 + (lane >> 4) * 8;
    short vals[8];
#pragma unroll
    for (int jj = 0; jj < 8; jj++) {
      int k = kbase + jj;
      float v;
      if (stage == 0)
        v = (k < 128) ? Wl1[(size_t)k * HID + ncol] : Wr1[(size_t)(k - 128) * HID + ncol];
      else
        v = (ncol < 128) ? Wl2[(size_t)k * DIM + ncol] : Wr2[(size_t)k * DIM + (ncol - 128)];
      vals[jj] = f2bf(v);
    }
    short* outp = (stage == 0 ? Wf1 : Wf2) + ((size_t)(n * 8 + kk) << 9) + lane * 8;
    *(short4*)(outp)     = make_short4(vals[0], vals[1], vals[2], vals[3]);
    *(short4*)(outp + 4) = make_short4(vals[4], vals[5], vals[6], vals[7]);
  }
}

// ================= CSR scans =================
__global__ __launch_bounds__(256) void scan1_kernel(const int* __restrict__ degi,
                                                    int* __restrict__ pre,
                                                    int* __restrict__ bsum) {
  __shared__ int s[256];
  int tid = threadIdx.x;
  int i = blockIdx.x * 256 + tid;
  int v = (i < NN) ? degi[i] : 0;
  s[tid] = v;
  __syncthreads();
#pragma unroll
  for (int off = 1; off < 256; off <<= 1) {
    int t = (tid >= off) ? s[tid - off] : 0;
    __syncthreads();
    s[tid] += t;
    __syncthreads();
  }
  if (i < NN) pre[i] = s[tid] - v;
  if (tid == 255) bsum[blockIdx.x] = s[255];
}

// merged scan2+scan3: each block reduces its own bsum prefix, then writes rowptr.
// Also zeroes cnt[] (consumed by csr_scatter) — removes half the up-front memset.
__global__ __launch_bounds__(256) void scan23_kernel(const int* __restrict__ pre,
                                                     const int* __restrict__ bsum,
                                                     int* __restrict__ rowptr,
                                                     int* __restrict__ cnt) {
  __shared__ int sm[256];
  int tid = threadIdx.x;
  int nb = blockIdx.x;
  int v = 0;
  for (int i = tid; i < nb; i += 256) v += bsum[i];   // <=3 iters
  sm[tid] = v;
  __syncthreads();
#pragma unroll
  for (int off = 128; off > 0; off >>= 1) {
    if (tid < off) sm[tid] += sm[tid + off];
    __syncthreads();
  }
  int base = sm[0];
  int i = nb * 256 + tid;
  if (i < NN) {
    rowptr[i] = pre[i] + base;
    cnt[i] = 0;
  }
  if (i == 0) rowptr[NN] = NE;
}

// stores (src, edge_id) per CSR slot
__global__ __launch_bounds__(256) void csr_scatter_kernel(const int* __restrict__ src,
                                                          const int* __restrict__ dst,
                                                          const int* __restrict__ rowptr,
                                                          int* __restrict__ cnt,
                                                          int2* __restrict__ epk) {
  int e = blockIdx.x * 256 + threadIdx.x;
  if (e >= NE) return;
  int d = dst[e];
  int pos = rowptr[d] + atomicAdd(&cnt[d], 1);
  epk[pos] = make_int2(src[e], e);
}

// ================= fused MFMA: gather1 + both GEMMs, h stays in LDS =================
// Staging does the neighbor-mean gather IN-KERNEL. xb strictly read-only here.
// Stage-2 stages BOTH halves in the tile: cols 0..127 = hW (bf16 -> hW_out),
// cols 128..255 = partial h@Wr2+bl2 (bf16, streamed into the FIRST 256B of each
// node's f32 dref row — gather2 reads it there before overwriting with f32).
__global__ __launch_bounds__(512, 4) void fused_mfma_kernel(
    const int* __restrict__ rowptr, const int2* __restrict__ epk,
    const short* __restrict__ xb, short* __restrict__ hW_out,
    const short* __restrict__ Wf1, const float* __restrict__ bl1,
    const short* __restrict__ Wf2, const float* __restrict__ bl2,
    float* __restrict__ dref) {
  __shared__ __align__(16) short tile[MBLK][LDK];   // 67.6 KB -> 2 blocks/CU
  const int tid = threadIdx.x;
  const int row0 = blockIdx.x * MBLK;

  // ---- staging: A_cat = [mean_gather(xb) | xb_own] per row, 16-lane groups ----
  {
    const int grp = tid >> 4;        // 0..31
    const int l   = tid & 15;
    for (int rr = grp; rr < MBLK; rr += 32) {
      int row = row0 + rr;
      if (row < NN) {
        bf16x8 xv = *(const bf16x8*)(xb + (size_t)row * DIM + l * 8);
        *(bf16x8*)&tile[rr][DIM + l * 8] = xv;
        int b = rowptr[row], e = rowptr[row + 1];
        float acc[8] = {0.f, 0.f, 0.f, 0.f, 0.f, 0.f, 0.f, 0.f};
        for (int j = b; j < e; j += 4) {
          int i1 = (j + 1 < e) ? j + 1 : j;
          int i2 = (j + 2 < e) ? j + 2 : j;
          int i3 = (j + 3 < e) ? j + 3 : j;
          int s0 = epk[j].x, s1 = epk[i1].x, s2 = epk[i2].x, s3 = epk[i3].x;
          bf16x8 r0 = *(const bf16x8*)(xb + (size_t)s0 * DIM + l * 8);
          bf16x8 r1 = *(const bf16x8*)(xb + (size_t)s1 * DIM + l * 8);
          bf16x8 r2 = *(const bf16x8*)(xb + (size_t)s2 * DIM + l * 8);
          bf16x8 r3 = *(const bf16x8*)(xb + (size_t)s3 * DIM + l * 8);
          float m1 = (j + 1 < e) ? 1.f : 0.f;
          float m2 = (j + 2 < e) ? 1.f : 0.f;
          float m3 = (j + 3 < e) ? 1.f : 0.f;
#pragma unroll
          for (int k = 0; k < 8; k++)
            acc[k] += bf2f(r0[k]) + m1 * bf2f(r1[k]) + m2 * bf2f(r2[k]) + m3 * bf2f(r3[k]);
        }
        float inv = 1.0f / fmaxf((float)(e - b), 1.0f);
        bf16x8 ov;
#pragma unroll
        for (int k = 0; k < 8; k++) ov[k] = f2bf(acc[k] * inv);
        *(bf16x8*)&tile[rr][l * 8] = ov;
      } else {
        bf16x8 z = {0, 0, 0, 0, 0, 0, 0, 0};
        *(bf16x8*)&tile[rr][l * 8] = z;
        *(bf16x8*)&tile[rr][DIM + l * 8] = z;
      }
    }
  }
  __syncthreads();

  const int lane = tid & 63;
  const int wv   = tid >> 6;          // 0..7
  const int c    = lane & 15;
  const int quad = lane >> 4;
  const int wrow = (wv & 3) * 32;     // row quarter (32 rows = 2 groups of 16)
  const int ch   = wv >> 2;           // col half

  // ---- stage 1: h = relu(A_cat @ W1 + bl1) -> LDS ----
  {
    bf16x8 af[2][8];
#pragma unroll
    for (int rg = 0; rg < 2; rg++)
#pragma unroll
      for (int kk = 0; kk < 8; kk++)
        af[rg][kk] = *(const bf16x8*)&tile[wrow + rg * 16 + c][kk * 32 + quad * 8];
    __syncthreads();                  // A in regs everywhere -> safe to overwrite tile

#pragma unroll 2
    for (int nn = 0; nn < 8; nn++) {
      int n = ch * 8 + nn;
      const short* wq = Wf1 + ((size_t)(n * 8) << 9) + lane * 8;
      bf16x8 bw[8];
#pragma unroll
      for (int kk = 0; kk < 8; kk++)
        bw[kk] = *(const bf16x8*)(wq + ((size_t)kk << 9));
      f32x4 a0 = {0.f, 0.f, 0.f, 0.f}, a1 = {0.f, 0.f, 0.f, 0.f};
      __builtin_amdgcn_s_setprio(1);
#pragma unroll
      for (int kk = 0; kk < 8; kk++) {
        a0 = __builtin_amdgcn_mfma_f32_16x16x32_bf16(af[0][kk], bw[kk], a0, 0, 0, 0);
        a1 = __builtin_amdgcn_mfma_f32_16x16x32_bf16(af[1][kk], bw[kk], a1, 0, 0, 0);
      }
      __builtin_amdgcn_s_setprio(0);
      float bv = bl1[n * 16 + c];
#pragma unroll
      for (int i = 0; i < 4; i++) {
        tile[wrow +      quad * 4 + i][n * 16 + c] = f2bf(fmaxf(a0[i] + bv, 0.0f));
        tile[wrow + 16 + quad * 4 + i][n * 16 + c] = f2bf(fmaxf(a1[i] + bv, 0.0f));
      }
    }
  }
  __syncthreads();

  // ---- stage 2: [hW | partial+bl2] -> tile (both halves bf16), then stream out ----
  {
    bf16x8 af[2][8];
#pragma unroll
    for (int rg = 0; rg < 2; rg++)
#pragma unroll
      for (int kk = 0; kk < 8; kk++)
        af[rg][kk] = *(const bf16x8*)&tile[wrow + rg * 16 + c][kk * 32 + quad * 8];
    __syncthreads();                   // all waves done reading h -> safe to overwrite

#pragma unroll 2
    for (int nn = 0; nn < 8; nn++) {
      int n = ch * 8 + nn;
      const short* wq = Wf2 + ((size_t)(n * 8) << 9) + lane * 8;
      bf16x8 bw[8];
#pragma unroll
      for (int kk = 0; kk < 8; kk++)
        bw[kk] = *(const bf16x8*)(wq + ((size_t)kk << 9));
      f32x4 a0 = {0.f, 0.f, 0.f, 0.f}, a1 = {0.f, 0.f, 0.f, 0.f};
      __builtin_amdgcn_s_setprio(1);
#pragma unroll
      for (int kk = 0; kk < 8; kk++) {
        a0 = __builtin_amdgcn_mfma_f32_16x16x32_bf16(af[0][kk], bw[kk], a0, 0, 0, 0);
        a1 = __builtin_amdgcn_mfma_f32_16x16x32_bf16(af[1][kk], bw[kk], a1, 0, 0, 0);
      }
      __builtin_amdgcn_s_setprio(0);
      int col = n * 16 + c;
      float bv = (ch == 1) ? bl2[col - 128] : 0.0f;   // bias only on the Wr2 half
#pragma unroll
      for (int i = 0; i < 4; i++) {
        tile[wrow +      quad * 4 + i][col] = f2bf(a0[i] + bv);
        tile[wrow + 16 + quad * 4 + i][col] = f2bf(a1[i] + bv);
      }
    }
  }
  __syncthreads();

  // stream both halves out coalesced: hW -> hW_out; partial bf16 -> first 256B
  // of the node's f32 dref row (gather2 reads it before overwriting with f32)
  for (int idx = tid; idx < MBLK * 32; idx += 512) {
    int r   = idx >> 5;
    int c16 = idx & 31;
    int row = row0 + r;
    if (row < NN) {
      int4 v = *(const int4*)&tile[r][c16 * 8];
      if (c16 < 16)
        *(int4*)(hW_out + (size_t)row * DIM + c16 * 8) = v;
      else
        *(int4*)((short*)(dref + (size_t)row * DIM) + (c16 - 16) * 8) = v;
    }
  }
}

// ================= gather2: dref = partial(bf16, in-row) + mean(hWb[src]) ============
// Reads the bf16 partial from the first 256B of the node's dref row, then
// overwrites the row with the full f32 result. The f32 stores data-depend on
// the partial loads (fin <- p), so the wave drains the reads before writing.
// Also writes the bf16 shadow into drefb (= dead xb).
__global__ __launch_bounds__(256) void gather2_kernel(const int* __restrict__ rowptr,
                                                      const int2* __restrict__ epk,
                                                      const short* __restrict__ hWb,
                                                      short* __restrict__ drefb,
                                                      float* dref) {
  int t = blockIdx.x * 256 + threadIdx.x;
  int node = t >> 4, l = t & 15;
  if (node >= NN) return;
  int b = rowptr[node], e = rowptr[node + 1];
  float* dr = dref + (size_t)node * DIM;
  bf16x8 p = *(const bf16x8*)((const short*)dr + l * 8);   // hoisted bf16 partial
  float acc[8] = {0.f, 0.f, 0.f, 0.f, 0.f, 0.f, 0.f, 0.f};
  for (int j = b; j < e; j += 4) {
    int i1 = (j + 1 < e) ? j + 1 : j;
    int i2 = (j + 2 < e) ? j + 2 : j;
    int i3 = (j + 3 < e) ? j + 3 : j;
    int s0 = epk[j].x, s1 = epk[i1].x, s2 = epk[i2].x, s3 = epk[i3].x;
    bf16x8 r0 = *(const bf16x8*)(hWb + (size_t)s0 * DIM + l * 8);
    bf16x8 r1 = *(const bf16x8*)(hWb + (size_t)s1 * DIM + l * 8);
    bf16x8 r2 = *(const bf16x8*)(hWb + (size_t)s2 * DIM + l * 8);
    bf16x8 r3 = *(const bf16x8*)(hWb + (size_t)s3 * DIM + l * 8);
    float m1 = (j + 1 < e) ? 1.f : 0.f;
    float m2 = (j + 2 < e) ? 1.f : 0.f;
    float m3 = (j + 3 < e) ? 1.f : 0.f;
#pragma unroll
    for (int k = 0; k < 8; k++)
      acc[k] += bf2f(r0[k]) + m1 * bf2f(r1[k]) + m2 * bf2f(r2[k]) + m3 * bf2f(r3[k]);
  }
  float inv = 1.0f / fmaxf((float)(e - b), 1.0f);
  float fin[8];
  bf16x8 ov;
#pragma unroll
  for (int k = 0; k < 8; k++) {
    fin[k] = bf2f(p[k]) + acc[k] * inv;
    ov[k] = f2bf(fin[k]);
  }
  *(float4*)(dr + l * 8)     = make_float4(fin[0], fin[1], fin[2], fin[3]);
  *(float4*)(dr + l * 8 + 4) = make_float4(fin[4], fin[5], fin[6], fin[7]);
  *(bf16x8*)(drefb + (size_t)node * DIM + l * 8) = ov;
}

// ================= edge scoring, CSR-node-parallel: dst row register-cached ==========
__global__ __launch_bounds__(256) void score_kernel(const int* __restrict__ rowptr,
                                                    const int2* __restrict__ epk,
                                                    const short* __restrict__ drefb,
                                                    float* __restrict__ out) {
  int t = blockIdx.x * 256 + threadIdx.x;
  int node = t >> 4, l = t & 15;
  if (node >= NN) return;
  int b = rowptr[node], e = rowptr[node + 1];
  if (b == e) return;
  bf16x8 d = *(const bf16x8*)(drefb + (size_t)node * DIM + l * 8);
  float f[8];
#pragma unroll
  for (int k = 0; k < 8; k++) f[k] = bf2f(d[k]);
  for (int j = b; j < e; j += 4) {
    int i1 = (j + 1 < e) ? j + 1 : j;
    int i2 = (j + 2 < e) ? j + 2 : j;
    int i3 = (j + 3 < e) ? j + 3 : j;
    int2 p0 = epk[j], p1 = epk[i1], p2 = epk[i2], p3 = epk[i3];
    bf16x8 r0 = *(const bf16x8*)(drefb + (size_t)p0.x * DIM + l * 8);
    bf16x8 r1 = *(const bf16x8*)(drefb + (size_t)p1.x * DIM + l * 8);
    bf16x8 r2 = *(const bf16x8*)(drefb + (size_t)p2.x * DIM + l * 8);
    bf16x8 r3 = *(const bf16x8*)(drefb + (size_t)p3.x * DIM + l * 8);
    float s0 = 0.f, s1 = 0.f, s2 = 0.f, s3 = 0.f;
#pragma unroll
    for (int k = 0; k < 8; k++) {
      s0 += bf2f(r0[k]) * f[k];
      s1 += bf2f(r1[k]) * f[k];
      s2 += bf2f(r2[k]) * f[k];
      s3 += bf2f(r3[k]) * f[k];
    }
#pragma unroll
    for (int off = 1; off < 16; off <<= 1) {
      s0 += __shfl_xor(s0, off, 16);
      s1 += __shfl_xor(s1, off, 16);
      s2 += __shfl_xor(s2, off, 16);
      s3 += __shfl_xor(s3, off, 16);
    }
    if (l == 0) {
      out[p0.y] = s0;
      if (j + 1 < e) out[p1.y] = s1;
      if (j + 2 < e) out[p2.y] = s2;
      if (j + 3 < e) out[p3.y] = s3;
    }
  }
}

extern "C" void kernel_launch(void* const* d_in, const int* in_sizes, int n_in,
                              void* d_out, int out_size, void* d_ws, size_t ws_size,
                              hipStream_t stream) {
  const int* ei    = (const int*)d_in[0];
  const int* src   = ei;
  const int* dst   = ei + NE;
  // d_in[1] = edge_attr (unused by the reference)
  const float* movie = (const float*)d_in[2];
  const float* user  = (const float*)d_in[3];
  const float* Wl1   = (const float*)d_in[4];
  const float* bl1   = (const float*)d_in[5];
  const float* Wr1   = (const float*)d_in[6];
  const float* Wl2   = (const float*)d_in[7];
  const float* bl2   = (const float*)d_in[8];
  const float* Wr2   = (const float*)d_in[9];

  float* out  = (float*)d_out;       // [NE] ratings
  float* dref = out + NE;            // [NN*DIM] refined (f32 output; also carries
                                     //   the bf16 partial in each row's first 256B)

  // workspace (~84 MB): ints | epk | xb(+drefb alias) | hWb | Wf1 | Wf2
  int* degi   = (int*)d_ws;                    // [NN] (zeroed)
  int* cnt    = degi + NN;                     // [NN] (zeroed by scan23)
  int* pre    = cnt + NN;                      // [NN]
  int* bsum   = pre + NN;                      // [1024]
  int* rowptr = bsum + 1024;                   // [NN+1]
  int2* epk   = (int2*)(((uintptr_t)(rowptr + NN + 1) + 7) & ~(uintptr_t)7);  // [NE]
  short* xb   = (short*)(((uintptr_t)(epk + NE) + 15) & ~(uintptr_t)15);  // [NN*DIM] bf16
  short* hWb  = xb + (size_t)NN * DIM;         // [NN*DIM] bf16 (h@Wl2, from fused)
  short* Wf1  = hWb + (size_t)NN * DIM;        // [65536]
  short* Wf2  = Wf1 + 65536;                   // [65536]
  short* drefb = xb;                           // alias: xb dead after fused

  hipMemsetAsync(degi, 0, (size_t)NN * sizeof(int), stream);

  prep_kernel<<<NB_DEG + NB_CVX + NB_CVW, 256, 0, stream>>>(
      dst, degi, movie, user, xb, Wl1, Wr1, Wl2, Wr2, Wf1, Wf2);
  scan1_kernel<<<NB_SCAN, 256, 0, stream>>>(degi, pre, bsum);
  scan23_kernel<<<NB_SCAN, 256, 0, stream>>>(pre, bsum, rowptr, cnt);
  csr_scatter_kernel<<<(NE + 255) / 256, 256, 0, stream>>>(src, dst, rowptr, cnt, epk);
  fused_mfma_kernel<<<(NN + MBLK - 1) / MBLK, 512, 0, stream>>>(
      rowptr, epk, xb, hWb, Wf1, bl1, Wf2, bl2, dref);
  gather2_kernel<<<NN * 16 / 256, 256, 0, stream>>>(rowptr, epk, hWb, drefb, dref);
  score_kernel<<<NN * 16 / 256, 256, 0, stream>>>(rowptr, epk, drefb, out);
}